// Round 10
// baseline (140.755 us; speedup 1.0000x reference)
//
#include <hip/hip_runtime.h>
#include <math.h>

#define V  50257
#define H  1032
#define INW 2064
#define S  8192

// d_out flat layout (fp32): [output V][attn_context H][hidden H][attn_w S]
#define O_CTX  50257
#define O_HID  51289
#define O_ATTN 52321

// ws float offsets
#define OFF_GXP  0        // 2*3096 gx partials (chunk-major)
#define OFF_GHP  6192     // 2*3096 gh partials
#define OFF_HNEW 12384    // 1032
#define OFF_V    13416    // 1032 (zeroed by K1 block 0)
#define OFF_CTXV 14448    // 1032 (zeroed by K1 block 1)
#define OFF_SC   15480    // 8192 scores
#define OFF_SCP  23672    // 2*SC_B score softmax partials (m,s)
#define OFF_PART 24696    // 2*NPART lse partials

#define GRU_B   1548      // 6192 waves = 3096 rows x 2 K-chunks
#define VA_B    160       // 5 col-tiles x 32 j-chunks (33 rows each)
#define SC_B    512       // scores blocks: 4 waves x 4 rows = 16 rows/block
#define NPART   1571      // logits blocks; 4 waves x 8 rows, exact single sweep

typedef float fvec4 __attribute__((ext_vector_type(4)));

__device__ __forceinline__ float waveReduceSum(float v) {
#pragma unroll
  for (int off = 32; off > 0; off >>= 1) v += __shfl_down(v, off);
  return v;  // valid in lane 0
}

__device__ __forceinline__ float dot4(const float4 a, const float4 b) {
  return a.x * b.x + a.y * b.y + a.z * b.z + a.w * b.w;
}

// streamed-once load: nontemporal float4 dot against cached vector
__device__ __forceinline__ float ntdot(const fvec4* __restrict__ p, const float4 c) {
  fvec4 a = __builtin_nontemporal_load(p);
  return a.x * c.x + a.y * c.y + a.z * c.z + a.w * c.w;
}

// K1: GRU matvec partials. Wave g = b*4+wv: row j = g>>1, K-chunk c = g&1.
// Blocks 0/1 zero v/ctxv for later atomics.
__global__ __launch_bounds__(256) void gru_mv_kernel(
    const int* __restrict__ word, const float* __restrict__ emb,
    const float* __restrict__ lc, const float* __restrict__ ph,
    const float* __restrict__ W_ih, const float* __restrict__ W_hh,
    float* __restrict__ ws) {
  __shared__ __align__(16) float xh[INW + H];
  float* gxp = ws + OFF_GXP;
  float* ghp = ws + OFF_GHP;
  int t = threadIdx.x, wv = t >> 6, lane = t & 63, b = blockIdx.x;
  if (b == 0) for (int i = t; i < H; i += 256) (ws + OFF_V)[i] = 0.f;
  if (b == 1) for (int i = t; i < H; i += 256) (ws + OFF_CTXV)[i] = 0.f;
  int w0 = word[0];
  for (int i = t; i < INW; i += 256) xh[i] = (i < H) ? emb[(size_t)w0 * H + i] : lc[i - H];
  for (int i = t; i < H; i += 256) xh[INW + i] = ph[i];
  __syncthreads();
  int g = b * 4 + wv;            // [0, 6192)
  int j = g >> 1, c = g & 1;     // row, K-chunk
  const fvec4* wi = (const fvec4*)(W_ih + (size_t)j * INW + c * (INW / 2));
  const float4* x4 = (const float4*)(xh + c * (INW / 2));
  float a0 = 0.f;
  for (int i = lane; i < INW / 8; i += 64) a0 += ntdot(wi + i, x4[i]);   // 258 f4
  const fvec4* wh = (const fvec4*)(W_hh + (size_t)j * H + c * (H / 2));
  const float4* h4 = (const float4*)(xh + INW + c * (H / 2));
  float a1 = 0.f;
  for (int i = lane; i < H / 8; i += 64) a1 += ntdot(wh + i, h4[i]);     // 129 f4
  a0 = waveReduceSum(a0); a1 = waveReduceSum(a1);
  if (lane == 0) { gxp[c * 3096 + j] = a0; ghp[c * 3096 + j] = a1; }
}

__device__ __forceinline__ float gru_elem(
    const float* __restrict__ gxp, const float* __restrict__ ghp,
    const float* __restrict__ b_ih, const float* __restrict__ b_hh,
    const float* __restrict__ ph, int k) {
  float gxr = gxp[k] + gxp[3096 + k],           ghr = ghp[k] + ghp[3096 + k];
  float gxz = gxp[H + k] + gxp[3096 + H + k],   ghz = ghp[H + k] + ghp[3096 + H + k];
  float gxn = gxp[2 * H + k] + gxp[3096 + 2 * H + k];
  float ghn = ghp[2 * H + k] + ghp[3096 + 2 * H + k];
  float r = 1.f / (1.f + expf(-(gxr + ghr + b_ih[k] + b_hh[k])));
  float z = 1.f / (1.f + expf(-(gxz + ghz + b_ih[H + k] + b_hh[H + k])));
  float n = tanhf(gxn + b_ih[2 * H + k] + r * (ghn + b_hh[2 * H + k]));
  return (1.f - z) * n + z * ph[k];
}

// K2: blocks [0,VA_B): v += W_a^T hnew (hnew slice finalized redundantly in-block);
// blocks [VA_B, VA_B+4): finalize + write hnew/hid_out.
__global__ __launch_bounds__(256) void vafin_kernel(
    const float* __restrict__ W_a, const float* __restrict__ ph,
    const float* __restrict__ b_ih, const float* __restrict__ b_hh,
    float* __restrict__ ws, float* __restrict__ out) {
  __shared__ float hsh[33];
  const float* gxp = ws + OFF_GXP;
  const float* ghp = ws + OFF_GHP;
  int b = blockIdx.x, t = threadIdx.x;
  if (b < VA_B) {
    int ct = b % 5, jc = b / 5;        // jc in [0,32)
    int j0 = jc * 33;
    int nj = min(33, H - j0);
    if (t < nj) hsh[t] = gru_elem(gxp, ghp, b_ih, b_hh, ph, j0 + t);
    __syncthreads();
    int k = ct * 256 + t;
    if (k < H) {
      float acc = 0.f;
      for (int j = 0; j < nj; ++j)
        acc += __builtin_nontemporal_load(&W_a[(size_t)(j0 + j) * H + k]) * hsh[j];
      atomicAdd(ws + OFF_V + k, acc);
    }
  } else {
    int base = (b - VA_B) * 258;
    for (int kk = t; kk < 258; kk += 256) {
      int k = base + kk;
      float hv = gru_elem(gxp, ghp, b_ih, b_hh, ph, k);
      (ws + OFF_HNEW)[k] = hv;
      out[O_HID + k] = hv;
    }
  }
}

// K3: scores, 4 consecutive rows per wave (quad-stream), v staged in LDS,
// per-block softmax partial (m_b, s_b) over its 16 rows.
// (b_a dropped: constant shift cancels in softmax)
__global__ __launch_bounds__(256) void scores_kernel(
    const float* __restrict__ enc, float* __restrict__ ws) {
  __shared__ __align__(16) float sv[H];
  __shared__ float wm[4], wsv[4];
  int t = threadIdx.x, wv = t >> 6, lane = t & 63;
  for (int i = t; i < H; i += 256) sv[i] = (ws + OFF_V)[i];
  __syncthreads();
  int s0 = blockIdx.x * 16 + wv * 4;
  const float4* R0 = (const float4*)(enc + (size_t)s0 * H);
  const float4* R1 = (const float4*)(enc + (size_t)(s0 + 1) * H);
  const float4* R2 = (const float4*)(enc + (size_t)(s0 + 2) * H);
  const float4* R3 = (const float4*)(enc + (size_t)(s0 + 3) * H);
  const float4* v4 = (const float4*)sv;
  float a0 = 0.f, a1 = 0.f, a2 = 0.f, a3 = 0.f;
  for (int i = lane; i < H / 4; i += 64) {
    float4 c = v4[i];
    a0 += dot4(R0[i], c);
    a1 += dot4(R1[i], c);
    a2 += dot4(R2[i], c);
    a3 += dot4(R3[i], c);
  }
  a0 = waveReduceSum(a0); a1 = waveReduceSum(a1);
  a2 = waveReduceSum(a2); a3 = waveReduceSum(a3);
  if (lane == 0) {
    float* sc = ws + OFF_SC;
    sc[s0] = a0; sc[s0 + 1] = a1; sc[s0 + 2] = a2; sc[s0 + 3] = a3;
    float m = fmaxf(fmaxf(a0, a1), fmaxf(a2, a3));
    wm[wv] = m;
    wsv[wv] = expf(a0 - m) + expf(a1 - m) + expf(a2 - m) + expf(a3 - m);
  }
  __syncthreads();
  if (t == 0) {
    float m = wm[0], s = wsv[0];
    for (int q = 1; q < 4; ++q) {
      float nm = fmaxf(m, wm[q]);
      s = s * expf(m - nm) + wsv[q] * expf(wm[q] - nm);
      m = nm;
    }
    (ws + OFF_SCP)[2 * blockIdx.x]     = m;
    (ws + OFF_SCP)[2 * blockIdx.x + 1] = s;
  }
}

// K4: ctx[k] = sum_s w[s]*enc[s][k]; softmax (M, Sigma) rebuilt per block from the
// SC_B (m,s) partials (deterministic). 640 blocks: ct=b%5 col-tile, yc=b/5 row chunk.
// Col-tile 0 writes attn weights to d_out. enc read is last use -> nontemporal.
__global__ __launch_bounds__(256) void ctx_kernel(
    const float* __restrict__ enc, float* __restrict__ ws,
    float* __restrict__ out) {
  __shared__ float rm[256], rs[256];
  __shared__ float wsh[64];
  const float* scp = ws + OFF_SCP;
  const float* sc  = ws + OFF_SC;
  int t = threadIdx.x, b = blockIdx.x;
  float m = -3.4e38f, s = 0.f;
  for (int i = t; i < SC_B; i += 256) {
    float bm = scp[2 * i], bs = scp[2 * i + 1];
    float nm = fmaxf(m, bm);
    s = s * expf(m - nm) + bs * expf(bm - nm);
    m = nm;
  }
  rm[t] = m; rs[t] = s; __syncthreads();
  for (int off = 128; off; off >>= 1) {
    if (t < off) {
      float m2 = rm[t + off], s2 = rs[t + off];
      float nm = fmaxf(rm[t], m2);
      rs[t] = rs[t] * expf(rm[t] - nm) + s2 * expf(m2 - nm);
      rm[t] = nm;
    }
    __syncthreads();
  }
  float M = rm[0];
  float inv = 1.f / rs[0];
  int ct = b % 5, yc = b / 5;
  int s0 = yc * 64;
  if (t < 64) wsh[t] = expf(sc[s0 + t] - M) * inv;
  __syncthreads();
  if (ct == 0 && t < 64) out[O_ATTN + s0 + t] = wsh[t];
  int k = ct * 256 + t;
  if (k < H) {
    float acc = 0.f;
    for (int si = 0; si < 64; ++si)
      acc += wsh[si] * __builtin_nontemporal_load(&enc[(size_t)(s0 + si) * H + k]);
    atomicAdd(ws + OFF_CTXV + k, acc);
  }
}

// K5: logits, 8 consecutive full rows per wave (octo-stream ILP, nt loads),
// exact single sweep (1571 blocks x 4 waves x 8 rows = 50272 >= V).
// Raw logits -> d_out[0:V]; per-block lse partials. Block 0 emits ctx.
__global__ __launch_bounds__(256) void logits_kernel(
    const float* __restrict__ W_out, const float* __restrict__ b_out,
    float* __restrict__ ws, float* __restrict__ out) {
  __shared__ __align__(16) float joined[INW];
  __shared__ float pm[4], psv[4];
  int t = threadIdx.x, wv = t >> 6, lane = t & 63;
  for (int k = t; k < H; k += 256) {
    joined[k]     = (ws + OFF_HNEW)[k];
    joined[H + k] = (ws + OFF_CTXV)[k];
  }
  __syncthreads();
  if (blockIdx.x == 0) {
    for (int k = t; k < H; k += 256) out[O_CTX + k] = joined[H + k];
  }
  const float4* j4 = (const float4*)joined;
  int gw = blockIdx.x * 4 + wv;  // [0, 6284)
  int r0 = gw * 8;
  float lm = -3.4e38f, ls = 0.f;
  {
    const fvec4* R[8];
#pragma unroll
    for (int q = 0; q < 8; ++q) {
      int rq = min(r0 + q, V - 1);
      R[q] = (const fvec4*)(W_out + (size_t)rq * INW);
    }
    float a[8] = {0.f, 0.f, 0.f, 0.f, 0.f, 0.f, 0.f, 0.f};
    for (int i = lane; i < INW / 4; i += 64) {  // 516 f4, eight streams
      float4 c = j4[i];
#pragma unroll
      for (int q = 0; q < 8; ++q) a[q] += ntdot(R[q] + i, c);
    }
#pragma unroll
    for (int q = 0; q < 8; ++q) a[q] = waveReduceSum(a[q]);
    if (lane == 0) {
#pragma unroll
      for (int q = 0; q < 8; ++q) {
        int r = r0 + q;
        if (r < V) {
          float x = a[q] + b_out[r];
          out[r] = x;
          float nm = fmaxf(lm, x);
          ls = ls * expf(lm - nm) + expf(x - nm);
          lm = nm;
        }
      }
    }
  }
  if (lane == 0) { pm[wv] = lm; psv[wv] = ls; }
  __syncthreads();
  if (t == 0) {
    float m = pm[0], sb = psv[0];
    for (int q = 1; q < 4; ++q) {
      float nm = fmaxf(m, pm[q]);
      sb = sb * expf(m - nm) + psv[q] * expf(pm[q] - nm);
      m = nm;
    }
    (ws + OFF_PART)[2 * blockIdx.x]     = m;
    (ws + OFF_PART)[2 * blockIdx.x + 1] = sb;
  }
}

// K6: combine partials (redundantly per block, deterministic) + subtract lse.
__global__ __launch_bounds__(256) void apply_kernel(
    float* __restrict__ out, const float* __restrict__ ws) {
  __shared__ float mm[256], ssv[256];
  const float* partials = ws + OFF_PART;
  int t = threadIdx.x;
  float m = -3.4e38f, s = 0.f;
  for (int i = t; i < NPART; i += 256) {
    float bm = partials[2 * i], bs = partials[2 * i + 1];
    float nm = fmaxf(m, bm);
    s = s * expf(m - nm) + bs * expf(bm - nm);
    m = nm;
  }
  mm[t] = m; ssv[t] = s; __syncthreads();
  for (int off = 128; off; off >>= 1) {
    if (t < off) {
      float m2 = mm[t + off], s2 = ssv[t + off];
      float nm = fmaxf(mm[t], m2);
      ssv[t] = ssv[t] * expf(mm[t] - nm) + s2 * expf(m2 - nm);
      mm[t] = nm;
    }
    __syncthreads();
  }
  float L = mm[0] + logf(ssv[0]);
  int i = blockIdx.x * 256 + t;
  if (i < V) out[i] -= L;
}

extern "C" void kernel_launch(void* const* d_in, const int* in_sizes, int n_in,
                              void* d_out, int out_size, void* d_ws, size_t ws_size,
                              hipStream_t stream) {
  const int*   word  = (const int*)d_in[0];
  const float* lc    = (const float*)d_in[1];
  const float* ph    = (const float*)d_in[2];
  const float* enc   = (const float*)d_in[3];
  const float* emb   = (const float*)d_in[4];
  const float* W_ih  = (const float*)d_in[5];
  const float* W_hh  = (const float*)d_in[6];
  const float* b_ih  = (const float*)d_in[7];
  const float* b_hh  = (const float*)d_in[8];
  const float* W_a   = (const float*)d_in[9];
  // d_in[10] = b_a: unused — constant shift of all attention scores, cancels in softmax.
  const float* W_out = (const float*)d_in[11];
  const float* b_out = (const float*)d_in[12];
  float* out = (float*)d_out;
  float* ws  = (float*)d_ws;

  gru_mv_kernel<<<GRU_B, 256, 0, stream>>>(word, emb, lc, ph, W_ih, W_hh, ws);
  vafin_kernel<<<VA_B + 4, 256, 0, stream>>>(W_a, ph, b_ih, b_hh, ws, out);
  scores_kernel<<<SC_B, 256, 0, stream>>>(enc, ws);
  ctx_kernel<<<640, 256, 0, stream>>>(enc, ws, out);
  logits_kernel<<<NPART, 256, 0, stream>>>(W_out, b_out, ws, out);
  apply_kernel<<<(V + 255) / 256, 256, 0, stream>>>(out, ws);
}

// Round 11
// 132.843 us; speedup vs baseline: 1.0596x; 1.0596x over previous
//
#include <hip/hip_runtime.h>
#include <math.h>

#define V  50257
#define H  1032
#define INW 2064
#define S  8192

// d_out flat layout (fp32): [output V][attn_context H][hidden H][attn_w S]
#define O_CTX  50257
#define O_HID  51289
#define O_ATTN 52321

// ws float offsets
#define OFF_GXP  0        // 2*3096 gx partials (chunk-major)
#define OFF_GHP  6192     // 2*3096 gh partials
#define OFF_HNEW 12384    // 1032
#define OFF_V    13416    // 1032 (zeroed by K1 block 0)
#define OFF_CTXV 14448    // 1032 (zeroed by K1 block 1)
#define OFF_SC   15480    // 8192 scores
#define OFF_SCP  23672    // 2*1024 score softmax partials (m,s)
#define OFF_PART 25720    // 2*NPART lse partials

#define GRU_B   1548      // 6192 waves = 3096 rows x 2 K-chunks
#define VA_B    160       // 5 col-tiles x 32 j-chunks (33 rows each)
#define SC_B    1024      // scores blocks: 4 waves x 2 rows = 8 rows/block
#define NPART   2048      // logits blocks / partial pairs

typedef float fvec4 __attribute__((ext_vector_type(4)));

__device__ __forceinline__ float waveReduceSum(float v) {
#pragma unroll
  for (int off = 32; off > 0; off >>= 1) v += __shfl_down(v, off);
  return v;  // valid in lane 0
}

__device__ __forceinline__ float dot4(const float4 a, const float4 b) {
  return a.x * b.x + a.y * b.y + a.z * b.z + a.w * b.w;
}

// streamed-once load: nontemporal float4 dot against cached vector
__device__ __forceinline__ float ntdot(const fvec4* __restrict__ p, const float4 c) {
  fvec4 a = __builtin_nontemporal_load(p);
  return a.x * c.x + a.y * c.y + a.z * c.z + a.w * c.w;
}

// K1: GRU matvec partials. Wave g = b*4+wv: row j = g>>1, K-chunk c = g&1.
// Blocks 0/1 zero v/ctxv for later atomics.
__global__ __launch_bounds__(256) void gru_mv_kernel(
    const int* __restrict__ word, const float* __restrict__ emb,
    const float* __restrict__ lc, const float* __restrict__ ph,
    const float* __restrict__ W_ih, const float* __restrict__ W_hh,
    float* __restrict__ ws) {
  __shared__ __align__(16) float xh[INW + H];
  float* gxp = ws + OFF_GXP;
  float* ghp = ws + OFF_GHP;
  int t = threadIdx.x, wv = t >> 6, lane = t & 63, b = blockIdx.x;
  if (b == 0) for (int i = t; i < H; i += 256) (ws + OFF_V)[i] = 0.f;
  if (b == 1) for (int i = t; i < H; i += 256) (ws + OFF_CTXV)[i] = 0.f;
  int w0 = word[0];
  for (int i = t; i < INW; i += 256) xh[i] = (i < H) ? emb[(size_t)w0 * H + i] : lc[i - H];
  for (int i = t; i < H; i += 256) xh[INW + i] = ph[i];
  __syncthreads();
  int g = b * 4 + wv;            // [0, 6192)
  int j = g >> 1, c = g & 1;     // row, K-chunk
  const fvec4* wi = (const fvec4*)(W_ih + (size_t)j * INW + c * (INW / 2));
  const float4* x4 = (const float4*)(xh + c * (INW / 2));
  float a0 = 0.f;
  for (int i = lane; i < INW / 8; i += 64) a0 += ntdot(wi + i, x4[i]);   // 258 f4
  const fvec4* wh = (const fvec4*)(W_hh + (size_t)j * H + c * (H / 2));
  const float4* h4 = (const float4*)(xh + INW + c * (H / 2));
  float a1 = 0.f;
  for (int i = lane; i < H / 8; i += 64) a1 += ntdot(wh + i, h4[i]);     // 129 f4
  a0 = waveReduceSum(a0); a1 = waveReduceSum(a1);
  if (lane == 0) { gxp[c * 3096 + j] = a0; ghp[c * 3096 + j] = a1; }
}

__device__ __forceinline__ float gru_elem(
    const float* __restrict__ gxp, const float* __restrict__ ghp,
    const float* __restrict__ b_ih, const float* __restrict__ b_hh,
    const float* __restrict__ ph, int k) {
  float gxr = gxp[k] + gxp[3096 + k],           ghr = ghp[k] + ghp[3096 + k];
  float gxz = gxp[H + k] + gxp[3096 + H + k],   ghz = ghp[H + k] + ghp[3096 + H + k];
  float gxn = gxp[2 * H + k] + gxp[3096 + 2 * H + k];
  float ghn = ghp[2 * H + k] + ghp[3096 + 2 * H + k];
  float r = 1.f / (1.f + expf(-(gxr + ghr + b_ih[k] + b_hh[k])));
  float z = 1.f / (1.f + expf(-(gxz + ghz + b_ih[H + k] + b_hh[H + k])));
  float n = tanhf(gxn + b_ih[2 * H + k] + r * (ghn + b_hh[2 * H + k]));
  return (1.f - z) * n + z * ph[k];
}

// K2: blocks [0,VA_B): v += W_a^T hnew (hnew slice finalized redundantly in-block);
// blocks [VA_B, VA_B+4): finalize + write hnew/hid_out.
__global__ __launch_bounds__(256) void vafin_kernel(
    const float* __restrict__ W_a, const float* __restrict__ ph,
    const float* __restrict__ b_ih, const float* __restrict__ b_hh,
    float* __restrict__ ws, float* __restrict__ out) {
  __shared__ float hsh[33];
  const float* gxp = ws + OFF_GXP;
  const float* ghp = ws + OFF_GHP;
  int b = blockIdx.x, t = threadIdx.x;
  if (b < VA_B) {
    int ct = b % 5, jc = b / 5;        // jc in [0,32)
    int j0 = jc * 33;
    int nj = min(33, H - j0);
    if (t < nj) hsh[t] = gru_elem(gxp, ghp, b_ih, b_hh, ph, j0 + t);
    __syncthreads();
    int k = ct * 256 + t;
    if (k < H) {
      float acc = 0.f;
      for (int j = 0; j < nj; ++j)
        acc += __builtin_nontemporal_load(&W_a[(size_t)(j0 + j) * H + k]) * hsh[j];
      atomicAdd(ws + OFF_V + k, acc);
    }
  } else {
    int base = (b - VA_B) * 258;
    for (int kk = t; kk < 258; kk += 256) {
      int k = base + kk;
      float hv = gru_elem(gxp, ghp, b_ih, b_hh, ph, k);
      (ws + OFF_HNEW)[k] = hv;
      out[O_HID + k] = hv;
    }
  }
}

// K3: scores, 2 consecutive rows per wave + per-block softmax partial (m_b, s_b).
// enc stays cached (re-read by ctx). (b_a dropped: cancels in softmax)
__global__ __launch_bounds__(256) void scores_kernel(
    const float* __restrict__ enc, float* __restrict__ ws) {
  __shared__ float wm[4], wsv[4];
  int t = threadIdx.x, wv = t >> 6, lane = t & 63;
  int s0 = blockIdx.x * 8 + wv * 2;
  const float4* R0 = (const float4*)(enc + (size_t)s0 * H);
  const float4* R1 = (const float4*)(enc + (size_t)(s0 + 1) * H);
  const float4* v4 = (const float4*)(ws + OFF_V);
  float a0 = 0.f, a1 = 0.f;
  for (int i = lane; i < H / 4; i += 64) {
    float4 c = v4[i];
    a0 += dot4(R0[i], c);
    a1 += dot4(R1[i], c);
  }
  a0 = waveReduceSum(a0); a1 = waveReduceSum(a1);
  if (lane == 0) {
    (ws + OFF_SC)[s0]     = a0;
    (ws + OFF_SC)[s0 + 1] = a1;
    float m = fmaxf(a0, a1);
    wm[wv] = m;
    wsv[wv] = expf(a0 - m) + expf(a1 - m);
  }
  __syncthreads();
  if (t == 0) {
    float m = wm[0], s = wsv[0];
    for (int q = 1; q < 4; ++q) {
      float nm = fmaxf(m, wm[q]);
      s = s * expf(m - nm) + wsv[q] * expf(wm[q] - nm);
      m = nm;
    }
    (ws + OFF_SCP)[2 * blockIdx.x]     = m;
    (ws + OFF_SCP)[2 * blockIdx.x + 1] = s;
  }
}

// K4: ctx[k] = sum_s w[s]*enc[s][k]; softmax (M, Sigma) rebuilt per block from the
// 1024 (m,s) partials (deterministic). 640 blocks: ct=b%5 col-tile, yc=b/5 row chunk.
// Col-tile 0 writes attn weights to d_out. enc read is last use -> nontemporal.
__global__ __launch_bounds__(256) void ctx_kernel(
    const float* __restrict__ enc, float* __restrict__ ws,
    float* __restrict__ out) {
  __shared__ float rm[256], rs[256];
  __shared__ float wsh[64];
  const float* scp = ws + OFF_SCP;
  const float* sc  = ws + OFF_SC;
  int t = threadIdx.x, b = blockIdx.x;
  float m = -3.4e38f, s = 0.f;
  for (int i = t; i < SC_B; i += 256) {
    float bm = scp[2 * i], bs = scp[2 * i + 1];
    float nm = fmaxf(m, bm);
    s = s * expf(m - nm) + bs * expf(bm - nm);
    m = nm;
  }
  rm[t] = m; rs[t] = s; __syncthreads();
  for (int off = 128; off; off >>= 1) {
    if (t < off) {
      float m2 = rm[t + off], s2 = rs[t + off];
      float nm = fmaxf(rm[t], m2);
      rs[t] = rs[t] * expf(rm[t] - nm) + s2 * expf(m2 - nm);
      rm[t] = nm;
    }
    __syncthreads();
  }
  float M = rm[0];
  float inv = 1.f / rs[0];
  int ct = b % 5, yc = b / 5;
  int s0 = yc * 64;
  if (t < 64) wsh[t] = expf(sc[s0 + t] - M) * inv;
  __syncthreads();
  if (ct == 0 && t < 64) out[O_ATTN + s0 + t] = wsh[t];
  int k = ct * 256 + t;
  if (k < H) {
    float acc = 0.f;
    for (int si = 0; si < 64; ++si)
      acc += wsh[si] * __builtin_nontemporal_load(&enc[(size_t)(s0 + si) * H + k]);
    atomicAdd(ws + OFF_CTXV + k, acc);
  }
}

// K5: logits, 4 consecutive full rows per wave (quad-stream ILP, nt loads),
// sweep stride 32768. Raw logits -> d_out[0:V]; per-block lse partials.
// Block 0 emits ctx to d_out.
__global__ __launch_bounds__(256) void logits_kernel(
    const float* __restrict__ W_out, const float* __restrict__ b_out,
    float* __restrict__ ws, float* __restrict__ out) {
  __shared__ __align__(16) float joined[INW];
  __shared__ float pm[4], psv[4];
  int t = threadIdx.x, wv = t >> 6, lane = t & 63;
  for (int k = t; k < H; k += 256) {
    joined[k]     = (ws + OFF_HNEW)[k];
    joined[H + k] = (ws + OFF_CTXV)[k];
  }
  __syncthreads();
  if (blockIdx.x == 0) {
    for (int k = t; k < H; k += 256) out[O_CTX + k] = joined[H + k];
  }
  const float4* j4 = (const float4*)joined;
  int gw = blockIdx.x * 4 + wv;  // [0, 8192)
  float lm = -3.4e38f, ls = 0.f;
  for (int r0 = gw * 4; r0 < V; r0 += 4 * NPART * 4) {
    int rc1 = min(r0 + 1, V - 1), rc2 = min(r0 + 2, V - 1), rc3 = min(r0 + 3, V - 1);
    const fvec4* R0 = (const fvec4*)(W_out + (size_t)r0 * INW);
    const fvec4* R1 = (const fvec4*)(W_out + (size_t)rc1 * INW);
    const fvec4* R2 = (const fvec4*)(W_out + (size_t)rc2 * INW);
    const fvec4* R3 = (const fvec4*)(W_out + (size_t)rc3 * INW);
    float a0 = 0.f, a1 = 0.f, a2 = 0.f, a3 = 0.f;
    for (int i = lane; i < INW / 4; i += 64) {  // 516 f4, four streams
      float4 c = j4[i];
      a0 += ntdot(R0 + i, c);
      a1 += ntdot(R1 + i, c);
      a2 += ntdot(R2 + i, c);
      a3 += ntdot(R3 + i, c);
    }
    a0 = waveReduceSum(a0); a1 = waveReduceSum(a1);
    a2 = waveReduceSum(a2); a3 = waveReduceSum(a3);
    if (lane == 0) {
      float av[4] = {a0, a1, a2, a3};
#pragma unroll
      for (int q = 0; q < 4; ++q) {
        int r = r0 + q;
        if (r < V) {
          float x = av[q] + b_out[r];
          out[r] = x;
          float nm = fmaxf(lm, x);
          ls = ls * expf(lm - nm) + expf(x - nm);
          lm = nm;
        }
      }
    }
  }
  if (lane == 0) { pm[wv] = lm; psv[wv] = ls; }
  __syncthreads();
  if (t == 0) {
    float m = pm[0], sb = psv[0];
    for (int q = 1; q < 4; ++q) {
      float nm = fmaxf(m, pm[q]);
      sb = sb * expf(m - nm) + psv[q] * expf(pm[q] - nm);
      m = nm;
    }
    (ws + OFF_PART)[2 * blockIdx.x]     = m;
    (ws + OFF_PART)[2 * blockIdx.x + 1] = sb;
  }
}

// K6: combine partials (redundantly per block, deterministic) + subtract lse.
__global__ __launch_bounds__(256) void apply_kernel(
    float* __restrict__ out, const float* __restrict__ ws) {
  __shared__ float mm[256], ssv[256];
  const float* partials = ws + OFF_PART;
  int t = threadIdx.x;
  float m = -3.4e38f, s = 0.f;
  for (int i = t; i < NPART; i += 256) {
    float bm = partials[2 * i], bs = partials[2 * i + 1];
    float nm = fmaxf(m, bm);
    s = s * expf(m - nm) + bs * expf(bm - nm);
    m = nm;
  }
  mm[t] = m; ssv[t] = s; __syncthreads();
  for (int off = 128; off; off >>= 1) {
    if (t < off) {
      float m2 = mm[t + off], s2 = ssv[t + off];
      float nm = fmaxf(mm[t], m2);
      ssv[t] = ssv[t] * expf(mm[t] - nm) + s2 * expf(m2 - nm);
      mm[t] = nm;
    }
    __syncthreads();
  }
  float L = mm[0] + logf(ssv[0]);
  int i = blockIdx.x * 256 + t;
  if (i < V) out[i] -= L;
}

extern "C" void kernel_launch(void* const* d_in, const int* in_sizes, int n_in,
                              void* d_out, int out_size, void* d_ws, size_t ws_size,
                              hipStream_t stream) {
  const int*   word  = (const int*)d_in[0];
  const float* lc    = (const float*)d_in[1];
  const float* ph    = (const float*)d_in[2];
  const float* enc   = (const float*)d_in[3];
  const float* emb   = (const float*)d_in[4];
  const float* W_ih  = (const float*)d_in[5];
  const float* W_hh  = (const float*)d_in[6];
  const float* b_ih  = (const float*)d_in[7];
  const float* b_hh  = (const float*)d_in[8];
  const float* W_a   = (const float*)d_in[9];
  // d_in[10] = b_a: unused — constant shift of all attention scores, cancels in softmax.
  const float* W_out = (const float*)d_in[11];
  const float* b_out = (const float*)d_in[12];
  float* out = (float*)d_out;
  float* ws  = (float*)d_ws;

  gru_mv_kernel<<<GRU_B, 256, 0, stream>>>(word, emb, lc, ph, W_ih, W_hh, ws);
  vafin_kernel<<<VA_B + 4, 256, 0, stream>>>(W_a, ph, b_ih, b_hh, ws, out);
  scores_kernel<<<SC_B, 256, 0, stream>>>(enc, ws);
  ctx_kernel<<<640, 256, 0, stream>>>(enc, ws, out);
  logits_kernel<<<NPART, 256, 0, stream>>>(W_out, b_out, ws, out);
  apply_kernel<<<(V + 255) / 256, 256, 0, stream>>>(out, ws);
}